// Round 11
// baseline (202.877 us; speedup 1.0000x reference)
//
#include <hip/hip_runtime.h>

typedef __attribute__((ext_vector_type(8))) short short8;
typedef __attribute__((ext_vector_type(4))) short s16x4;
typedef __attribute__((ext_vector_type(8))) __bf16 bf16x8;
typedef __attribute__((ext_vector_type(4))) __bf16 bf16x4;
typedef __attribute__((ext_vector_type(2))) __bf16 bf16x2;
typedef __attribute__((ext_vector_type(4))) float f32x4;
typedef __attribute__((ext_vector_type(2))) float f32x2;
typedef __attribute__((ext_vector_type(4))) unsigned uint4v;
typedef __attribute__((ext_vector_type(2))) unsigned uint2v;

__device__ inline f32x4 mfma_bf16(short8 a, short8 b, f32x4 c) {
    return __builtin_amdgcn_mfma_f32_16x16x32_bf16(
        __builtin_bit_cast(bf16x8, a), __builtin_bit_cast(bf16x8, b), c, 0, 0, 0);
}
// K=16 bf16 MFMA: A-frag layout A[m=l16][k=quad*4+j] == C/D layout of a prior
// MFMA transposed -> P needs no layout transform.
__device__ inline f32x4 mfma16(uint2v a, uint2v b, f32x4 c) {
#if __has_builtin(__builtin_amdgcn_mfma_f32_16x16x16_bf16)
    return __builtin_amdgcn_mfma_f32_16x16x16_bf16(
        __builtin_bit_cast(bf16x4, a), __builtin_bit_cast(bf16x4, b), c, 0, 0, 0);
#else
    return __builtin_amdgcn_mfma_f32_16x16x16bf16_1k(
        __builtin_bit_cast(s16x4, a), __builtin_bit_cast(s16x4, b), c, 0, 0, 0);
#endif
}

// fast exp2: bare v_exp_f32
__device__ inline float fexp2(float x) {
#if __has_builtin(__builtin_amdgcn_exp2f)
    return __builtin_amdgcn_exp2f(x);
#else
    return exp2f(x);
#endif
}

// fp32 -> bf16 via HW convert (v_cvt_pk_bf16_f32 on gfx950), RNE
__device__ inline short f2b(float f) {
    __bf16 h = (__bf16)f;
    return __builtin_bit_cast(short, h);
}
__device__ inline unsigned pkbf(float a, float b) {
    f32x2 v; v[0] = a; v[1] = b;
    bf16x2 h = __builtin_convertvector(v, bf16x2);
    return __builtin_bit_cast(unsigned, h);
}

__device__ inline short8 ld8(const short* p) { return *(const short8*)p; }
__device__ inline short8 ld8(const float* p) {
    f32x4 a = *(const f32x4*)p;
    f32x4 b = *(const f32x4*)(p + 4);
    uint4v q;
    q[0] = pkbf(a[0], a[1]); q[1] = pkbf(a[2], a[3]);
    q[2] = pkbf(b[0], b[1]); q[3] = pkbf(b[2], b[3]);
    return __builtin_bit_cast(short8, q);
}
__device__ inline void storeC(short* C, size_t i, float v) { C[i] = f2b(v); }
__device__ inline void storeC(float* C, size_t i, float v) { C[i] = v; }

// async global->LDS DMA, 16 B/lane: LDS dest = wave-uniform base + lane*16
__device__ inline void glds16(const short* g, short* ldsbase, int lane) {
#if __has_builtin(__builtin_amdgcn_global_load_lds)
    __builtin_amdgcn_global_load_lds(
        (const __attribute__((address_space(1))) void*)g,
        (__attribute__((address_space(3))) void*)ldsbase, 16, 0, 0);
#else
    *(short8*)(ldsbase + lane * 8) = *(const short8*)g;
#endif
}

// log2(e)/32 : folded into Q so softmax uses exp2 (bare v_exp_f32)
#define QSCALE 0.04508422052265167f

// ---------------------------------------------------------------------------
// fp32 -> bf16 bulk convert (x -> xbf in d_out scratch). n multiple of 2048.
// ---------------------------------------------------------------------------
__global__ __launch_bounds__(256) void cvt_bf16(
    const float* __restrict__ x, short* __restrict__ xb)
{
    size_t i = ((size_t)blockIdx.x * 256 + threadIdx.x) * 8;
    *(short8*)(xb + i) = ld8(x + i);
}

// ---------------------------------------------------------------------------
// W [K][N] fp32 row-major -> Wt [N][K] bf16 k-major. grid (N/64, K/64).
// ---------------------------------------------------------------------------
__global__ __launch_bounds__(256) void transpose_w(
    const float* __restrict__ W, short* __restrict__ Wt, int K, int N)
{
    __shared__ short T[64 * 72];
    const int tid = threadIdx.x;
    const int n0 = blockIdx.x * 64, k0 = blockIdx.y * 64;
    {
        const int kl = tid >> 2, nc = (tid & 3) * 16;
        const float* src = W + (size_t)(k0 + kl) * N + n0 + nc;
        float v[16];
        *(f32x4*)&v[0]  = *(const f32x4*)(src + 0);
        *(f32x4*)&v[4]  = *(const f32x4*)(src + 4);
        *(f32x4*)&v[8]  = *(const f32x4*)(src + 8);
        *(f32x4*)&v[12] = *(const f32x4*)(src + 12);
        #pragma unroll
        for (int j = 0; j < 16; ++j) T[(nc + j) * 72 + kl] = f2b(v[j]);
    }
    __syncthreads();
    {
        const int nl = tid >> 2, kc = (tid & 3) * 16;
        short8 w0 = *(const short8*)&T[nl * 72 + kc];
        short8 w1 = *(const short8*)&T[nl * 72 + kc + 8];
        short* dst = Wt + (size_t)(n0 + nl) * K + k0 + kc;
        *(short8*)dst = w0;
        *(short8*)(dst + 8) = w1;
    }
}

// ---------------------------------------------------------------------------
// V transpose: qkv (B*N,3072) bf16 cols 2048+h*64 -> vt[(b*16+h)][dim][2048].
// ---------------------------------------------------------------------------
__global__ __launch_bounds__(256) void vtrans(
    const short* __restrict__ qkv, short* __restrict__ vt)
{
    __shared__ short T[64 * 72];
    const int tid = threadIdx.x;
    const int nt = blockIdx.x * 64, bh = blockIdx.y;
    const int b = bh >> 4, h = bh & 15;
    {
        const int tok = tid >> 2, dc = (tid & 3) * 16;
        const short* src = qkv + ((size_t)b * 2048 + nt + tok) * 3072 + 2048 + h * 64 + dc;
        short8 v0 = *(const short8*)src;
        short8 v1 = *(const short8*)(src + 8);
        #pragma unroll
        for (int j = 0; j < 8; ++j) {
            T[(dc + j) * 72 + tok]     = v0[j];
            T[(dc + 8 + j) * 72 + tok] = v1[j];
        }
    }
    __syncthreads();
    {
        const int dim = tid >> 2, kc = (tid & 3) * 16;
        short8 w0 = *(const short8*)&T[dim * 72 + kc];
        short8 w1 = *(const short8*)&T[dim * 72 + kc + 8];
        short* dst = vt + ((size_t)bh * 64 + dim) * 2048 + nt + kc;
        *(short8*)dst = w0;
        *(short8*)(dst + 8) = w1;
    }
}

// ---------------------------------------------------------------------------
// GEMM via global_load_lds (m97 structure): C = A @ Bt^T (+bias), bf16.
// 128x128 tile, BK=32, unpadded LDS rows (32 shorts) + XOR chunk swizzle
// (chunk' = chunk ^ ((row>>1)&3)) applied on the DMA's per-lane global
// source address -> fragment reads land 2-way per bank (free).
// QSC: scale cols<1024 by log2(e)/32.
// ---------------------------------------------------------------------------
template <bool QSC, bool ADD_BIAS, typename TC>
__global__ __launch_bounds__(256) void gemm128(
    const short* __restrict__ A, const short* __restrict__ Bt,
    const float* __restrict__ bias, TC* __restrict__ C,
    int M, int N, int K, int lda)
{
    __shared__ __align__(16) short A_s[128 * 32];
    __shared__ __align__(16) short B_s[128 * 32];
    const int tid  = threadIdx.x;
    const int lane = tid & 63;
    const int wave = tid >> 6;
    const int quad = lane >> 4;
    const int l16  = lane & 15;
    const int wr   = wave >> 1;
    const int wc   = wave & 1;
    const int bm   = blockIdx.y * 128;
    const int bn   = blockIdx.x * 128;

    f32x4 acc[4][4];
    #pragma unroll
    for (int i = 0; i < 4; ++i)
        #pragma unroll
        for (int j = 0; j < 4; ++j)
            acc[i][j] = f32x4{0.f, 0.f, 0.f, 0.f};

    // DMA mapping: wave w covers LDS bytes w*2048 (+1024 for inst 1);
    // lane i -> slot (w*2+j)*64+i, row = slot>>2, stored chunk = i&3,
    // logical chunk = stored ^ ((row>>1)&3) (same for both insts: rows +16).
    const int r0 = wave * 32 + (lane >> 2);
    const int cl = (lane & 3) ^ ((r0 >> 1) & 3);
    const short* gA0 = A  + (size_t)(bm + r0) * lda      + cl * 8;
    const short* gA1 = A  + (size_t)(bm + r0 + 16) * lda + cl * 8;
    const short* gB0 = Bt + (size_t)(bn + r0) * K        + cl * 8;
    const short* gB1 = Bt + (size_t)(bn + r0 + 16) * K   + cl * 8;
    short* lA0 = &A_s[wave * 1024];
    short* lA1 = &A_s[wave * 1024 + 512];
    short* lB0 = &B_s[wave * 1024];
    short* lB1 = &B_s[wave * 1024 + 512];

    // reader swizzle: fragment row = wr*64+i*16+l16 -> (row>>1)&3 = (l16>>1)&3
    const int coff = (quad ^ ((l16 >> 1) & 3)) * 8;

    for (int k0 = 0; k0 < K; k0 += 32) {
        __syncthreads();                 // prior slab consumed
        glds16(gA0 + k0, lA0, lane);
        glds16(gA1 + k0, lA1, lane);
        glds16(gB0 + k0, lB0, lane);
        glds16(gB1 + k0, lB1, lane);
        __syncthreads();                 // DMA drained (vmcnt0 before barrier)

        short8 a[4], b[4];
        #pragma unroll
        for (int i = 0; i < 4; ++i)
            a[i] = *(const short8*)&A_s[(wr * 64 + i * 16 + l16) * 32 + coff];
        #pragma unroll
        for (int j = 0; j < 4; ++j)
            b[j] = *(const short8*)&B_s[(wc * 64 + j * 16 + l16) * 32 + coff];
        #pragma unroll
        for (int i = 0; i < 4; ++i)
            #pragma unroll
            for (int j = 0; j < 4; ++j)
                acc[i][j] = mfma_bf16(a[i], b[j], acc[i][j]);
    }

    const float scale = (QSC && bn < 1024) ? QSCALE : 1.0f;
    #pragma unroll
    for (int i = 0; i < 4; ++i) {
        #pragma unroll
        for (int j = 0; j < 4; ++j) {
            #pragma unroll
            for (int r = 0; r < 4; ++r) {
                int row = bm + wr * 64 + i * 16 + quad * 4 + r;
                int col = bn + wc * 64 + j * 16 + l16;
                float v = acc[i][j][r] * scale;
                if (ADD_BIAS) v += bias[col];
                storeC(C, (size_t)row * N + col, v);
            }
        }
    }
}

// ---------------------------------------------------------------------------
// Flash attention v7 (unchanged from round 10): 32 q-rows/wave, S^T MFMA ->
// bare v_exp_f32 + v_cvt_pk_bf16_f32 -> direct K=16 PV (no P roundtrip).
// ctx in-place over q columns. grid (2048/128, 32) = 512 blocks.
// ---------------------------------------------------------------------------
__global__ __launch_bounds__(256) void attn128(
    short* __restrict__ qkv, const short* __restrict__ vt)
{
    __shared__ short Ks[128 * 72];   // [key][dim]
    __shared__ short Vs[16 * 520];   // [g][dim][k&7], g = key>>3 (tile-local)

    const int tid  = threadIdx.x;
    const int lane = tid & 63;
    const int wave = tid >> 6;
    const int quad = lane >> 4;
    const int l16  = lane & 15;
    const int bh   = blockIdx.y, b = bh >> 4, h = bh & 15;
    const int qb   = blockIdx.x * 128;
    const size_t rowbase = (size_t)b * 2048;

    short8 aq[2][2];
    #pragma unroll
    for (int qg = 0; qg < 2; ++qg) {
        const short* qp = qkv + (rowbase + qb + wave * 32 + qg * 16 + l16) * 3072 + h * 64;
        aq[qg][0] = *(const short8*)(qp + quad * 8);
        aq[qg][1] = *(const short8*)(qp + 32 + quad * 8);
    }

    f32x4 o[2][4];
    #pragma unroll
    for (int qg = 0; qg < 2; ++qg)
        #pragma unroll
        for (int c = 0; c < 4; ++c) o[qg][c] = f32x4{0.f, 0.f, 0.f, 0.f};
    float rsum[2] = {0.f, 0.f};

    const int kkey = tid >> 1, kdc = (tid & 1) * 32;
    const int vdim = tid >> 2, vg0 = (tid & 3) * 4;
    const short* kbase = qkv + (rowbase + kkey) * 3072 + 1024 + h * 64 + kdc;
    const short* vbase = vt + ((size_t)bh * 64 + vdim) * 2048 + vg0 * 8;

    short8 kr0 = *(const short8*)(kbase);
    short8 kr1 = *(const short8*)(kbase + 8);
    short8 kr2 = *(const short8*)(kbase + 16);
    short8 kr3 = *(const short8*)(kbase + 24);
    short8 vr0 = *(const short8*)(vbase);
    short8 vr1 = *(const short8*)(vbase + 8);
    short8 vr2 = *(const short8*)(vbase + 16);
    short8 vr3 = *(const short8*)(vbase + 24);

    for (int kt = 0; kt < 2048; kt += 128) {
        __syncthreads();
        *(short8*)&Ks[kkey * 72 + kdc]      = kr0;
        *(short8*)&Ks[kkey * 72 + kdc + 8]  = kr1;
        *(short8*)&Ks[kkey * 72 + kdc + 16] = kr2;
        *(short8*)&Ks[kkey * 72 + kdc + 24] = kr3;
        *(short8*)&Vs[(vg0 + 0) * 520 + vdim * 8] = vr0;
        *(short8*)&Vs[(vg0 + 1) * 520 + vdim * 8] = vr1;
        *(short8*)&Vs[(vg0 + 2) * 520 + vdim * 8] = vr2;
        *(short8*)&Vs[(vg0 + 3) * 520 + vdim * 8] = vr3;
        if (kt + 128 < 2048) {
            const short* kp = kbase + (size_t)(kt + 128) * 3072;
            kr0 = *(const short8*)(kp);
            kr1 = *(const short8*)(kp + 8);
            kr2 = *(const short8*)(kp + 16);
            kr3 = *(const short8*)(kp + 24);
            const short* vp = vbase + kt + 128;
            vr0 = *(const short8*)(vp);
            vr1 = *(const short8*)(vp + 8);
            vr2 = *(const short8*)(vp + 16);
            vr3 = *(const short8*)(vp + 24);
        }
        __syncthreads();

        #pragma unroll
        for (int cc = 0; cc < 2; ++cc) {
            f32x4 st[2][4];
            #pragma unroll
            for (int c4 = 0; c4 < 4; ++c4) {
                const int c = cc * 4 + c4;
                short8 ka0 = *(const short8*)&Ks[(c * 16 + l16) * 72 + quad * 8];
                short8 ka1 = *(const short8*)&Ks[(c * 16 + l16) * 72 + 32 + quad * 8];
                #pragma unroll
                for (int qg = 0; qg < 2; ++qg) {
                    f32x4 z = f32x4{0.f, 0.f, 0.f, 0.f};
                    z = mfma_bf16(ka0, aq[qg][0], z);
                    st[qg][c4] = mfma_bf16(ka1, aq[qg][1], z);
                }
            }
            uint2v pa[2][4];
            #pragma unroll
            for (int qg = 0; qg < 2; ++qg) {
                #pragma unroll
                for (int c4 = 0; c4 < 4; ++c4) {
                    float p0 = fexp2(st[qg][c4][0]);
                    float p1 = fexp2(st[qg][c4][1]);
                    float p2 = fexp2(st[qg][c4][2]);
                    float p3 = fexp2(st[qg][c4][3]);
                    rsum[qg] += (p0 + p1) + (p2 + p3);
                    uint2v pk;
                    pk[0] = pkbf(p0, p1);
                    pk[1] = pkbf(p2, p3);
                    pa[qg][c4] = pk;
                }
            }
            #pragma unroll
            for (int c2 = 0; c2 < 4; ++c2) {
                #pragma unroll
                for (int c4 = 0; c4 < 4; ++c4) {
                    const int c = cc * 4 + c4;
                    uint2v bv = *(const uint2v*)&Vs[(2 * c + (quad >> 1)) * 520
                                                    + (c2 * 16 + l16) * 8
                                                    + (quad & 1) * 4];
                    #pragma unroll
                    for (int qg = 0; qg < 2; ++qg)
                        o[qg][c2] = mfma16(pa[qg][c4], bv, o[qg][c2]);
                }
            }
        }
    }

    #pragma unroll
    for (int qg = 0; qg < 2; ++qg) {
        rsum[qg] += __shfl_xor(rsum[qg], 16, 64);
        rsum[qg] += __shfl_xor(rsum[qg], 32, 64);
    }

    #pragma unroll
    for (int qg = 0; qg < 2; ++qg) {
        #pragma unroll
        for (int r = 0; r < 4; ++r) {
            float inv = 1.0f / __shfl(rsum[qg], quad * 4 + r, 64);
            size_t row = rowbase + qb + wave * 32 + qg * 16 + quad * 4 + r;
            #pragma unroll
            for (int c2 = 0; c2 < 4; ++c2)
                qkv[row * 3072 + h * 64 + c2 * 16 + l16] = f2b(o[qg][c2][r] * inv);
        }
    }
}

// ---------------------------------------------------------------------------
extern "C" void kernel_launch(void* const* d_in, const int* in_sizes, int n_in,
                              void* d_out, int out_size, void* d_ws, size_t ws_size,
                              hipStream_t stream)
{
    const float* x    = (const float*)d_in[0];   // (2,2048,1024) fp32
    const float* Wqkv = (const float*)d_in[2];   // (1024,3072) fp32
    const float* Wout = (const float*)d_in[3];   // (1024,1024) fp32
    const float* bout = (const float*)d_in[4];   // (1024,) fp32
    float* out = (float*)d_out;                  // (2,2048,1024) fp32

    // ws: 32 MiB. qkv 24 MiB | 8 MiB region time-shared: Wqkvt -> vt -> Woutt
    // d_out doubles as scratch for xbf (first 8 MiB) until gemm2 overwrites.
    short* qkv    = (short*)d_ws;                // 4096 x 3072 bf16
    short* vtbuf  = qkv + (size_t)4096 * 3072;   // 8 MiB region
    short* wqkvt  = vtbuf;                       // 3072 x 1024 bf16
    short* woutt  = vtbuf;                       // 1024 x 1024 bf16
    short* xbf    = (short*)d_out;               // 4096 x 1024 bf16 (scratch)

    dim3 blk(256);
    cvt_bf16<<<dim3(2048), blk, 0, stream>>>(x, xbf);
    transpose_w<<<dim3(48, 16), blk, 0, stream>>>(Wqkv, wqkvt, 1024, 3072);
    gemm128<true, false, short><<<dim3(24, 32), blk, 0, stream>>>(
        xbf, wqkvt, nullptr, qkv, 4096, 3072, 1024, 1024);
    vtrans<<<dim3(32, 32), blk, 0, stream>>>(qkv, vtbuf);
    attn128<<<dim3(16, 32), blk, 0, stream>>>(qkv, vtbuf);
    transpose_w<<<dim3(16, 16), blk, 0, stream>>>(Wout, woutt, 1024, 1024);
    gemm128<false, true, float><<<dim3(8, 32), blk, 0, stream>>>(
        qkv, woutt, bout, out, 4096, 1024, 1024, 3072);
}